// Round 2
// baseline (569.516 us; speedup 1.0000x reference)
//
#include <hip/hip_runtime.h>

typedef __bf16 bf16x8 __attribute__((ext_vector_type(8)));
typedef float f32x4 __attribute__((ext_vector_type(4)));
typedef unsigned short u16x4 __attribute__((ext_vector_type(4)));
typedef unsigned short u16x8 __attribute__((ext_vector_type(8)));

#define MFMA16(a,b,c) __builtin_amdgcn_mfma_f32_16x16x32_bf16((a),(b),(c),0,0,0)

__device__ __forceinline__ unsigned short f2bf(float f){
  unsigned u = __builtin_bit_cast(unsigned, f);
  u += 0x7FFFu + ((u>>16)&1u);
  return (unsigned short)(u>>16);
}
__device__ __forceinline__ float bf2f(unsigned short h){
  unsigned u = ((unsigned)h)<<16;
  return __builtin_bit_cast(float, u);
}

// B/A fragment load from LDS laid out [row][k] (row = m for A, n for B), bf16.
// k-slot map: k = 4*(lane>>4) + (j&3) + 16*(j>>2) + 32*kp  (same map used for
// packed weights, so any hw k-permutation cancels).
__device__ __forceinline__ bf16x8 frag_ld(const unsigned short* base, int stride, int tile, int kp, int lane){
  const int row = (lane & 15) + 16*tile;
  const int col = 4*(lane >> 4) + 32*kp;
  const unsigned short* p = base + row*stride + col;
  u16x4 lo = *reinterpret_cast<const u16x4*>(p);
  u16x4 hi = *reinterpret_cast<const u16x4*>(p + 16);
  u16x8 v;
  v[0]=lo[0]; v[1]=lo[1]; v[2]=lo[2]; v[3]=lo[3];
  v[4]=hi[0]; v[5]=hi[1]; v[6]=hi[2]; v[7]=hi[3];
  return __builtin_bit_cast(bf16x8, v);
}

__device__ __forceinline__ bf16x8 afrag_ld(const unsigned short* wf, int mt, int KP, int kp, int lane){
  const unsigned short* p = wf + (size_t)(((mt*KP + kp)<<6) + lane)*8;
  u16x8 v = *reinterpret_cast<const u16x8*>(p);
  return __builtin_bit_cast(bf16x8, v);
}

// Pack W^T (from W[K][M] f32 row-major) into MFMA A-fragment order, bf16:
// dst[((mt*KP+kp)*64+lane)*8 + j] = W[4*(lane>>4)+(j&3)+16*(j>>2)+32*kp][16*mt+(lane&15)]
__global__ void pack_w_kernel(const float* __restrict__ src, unsigned short* __restrict__ dst,
                              int MT, int KP, int M){
  int tid = blockIdx.x*256 + threadIdx.x;
  if (tid >= MT*KP*64) return;
  int lane = tid & 63;
  int t2 = tid >> 6;
  int kp = t2 % KP;
  int mt = t2 / KP;
  int m = 16*mt + (lane & 15);
  int g = lane >> 4;
  u16x8 v;
#pragma unroll
  for (int j = 0; j < 8; ++j) {
    int k = 4*g + (j&3) + 16*(j>>2) + 32*kp;
    v[j] = f2bf(src[k*M + m]);
  }
  *reinterpret_cast<u16x8*>(&dst[(size_t)tid*8]) = v;
}

// biasT[h][key][q] = table[rel_idx(q,key)*4 + h]; replicates np.meshgrid 'xy'
// (d and h coordinate roles swapped relative to token layout -- intentional).
__global__ void prep_bias_kernel(const float* __restrict__ table, float* __restrict__ biasT){
  int tid = blockIdx.x*256 + threadIdx.x;
  if (tid >= 4*64*64) return;
  int q = tid & 63, key = (tid>>6)&63, h = tid>>12;
  int da = ((q>>2)&3) - ((key>>2)&3) + 3;
  int ha = (q>>4)     - (key>>4)     + 3;
  int wa = (q&3)      - (key&3)      + 3;
  int idx = (da*7 + ha)*7 + wa;
  biasT[tid] = table[idx*4 + h];
}

__global__ __launch_bounds__(256, 2)
void swin_block_kernel(const float* __restrict__ x,
                       const float* __restrict__ n1s, const float* __restrict__ n1b,
                       const unsigned short* __restrict__ wqkv,
                       const float* __restrict__ biasT,
                       const unsigned short* __restrict__ wproj,
                       const float* __restrict__ projb,
                       const float* __restrict__ n2s, const float* __restrict__ n2b,
                       const unsigned short* __restrict__ w1f, const float* __restrict__ b1,
                       const unsigned short* __restrict__ w2f, const float* __restrict__ b2,
                       float* __restrict__ out)
{
  // Arena A: xn -> o -> attn-staging -> xn2 -> mlp-staging, [64][140] bf16
  __shared__ unsigned short ldsA[64*140];
  // Arena B: per-head q[64][36], k[64][36], vT[32][72]; p[64][72] overlays q+k.
  // Reused after attention for MLP hidden [64][268] (chunked 2x256).
  __shared__ unsigned short ldsB[4*6912];
  __shared__ int rid_s[64];

  const int tid  = threadIdx.x;
  const int lane = tid & 63;
  const int w    = tid >> 6;      // wave id = head id
  const int g    = lane >> 4;
  const int l15  = lane & 15;

  // ---- window decode ----
  const int wb = blockIdx.x;
  const int b  = wb >> 11;
  const int r0 = wb & 2047;
  const int bd = r0 >> 8, bh = (r0 >> 4) & 15, bwi = r0 & 15;

  // ---- phase 0: load x (roll -2 fused), LN1, write xn bf16 to arena A ----
  const int t = tid >> 2, qtr = tid & 3;
  const int wd = t >> 4, wh = (t >> 2) & 3, ww = t & 3;
  const int dco = (bd*4 + wd + 2) & 31;
  const int hco = (bh*4 + wh + 2) & 63;
  const int wco = (bwi*4 + ww + 2) & 63;
  const long tokl = ((long)((b*32 + dco)*64 + hco))*64 + wco;
  const float* xrow = x + tokl*128 + qtr*32;

  float xr[32];
  float s = 0.f, sq = 0.f;
#pragma unroll
  for (int i = 0; i < 8; ++i) {
    float4 v = reinterpret_cast<const float4*>(xrow)[i];
    xr[4*i+0]=v.x; xr[4*i+1]=v.y; xr[4*i+2]=v.z; xr[4*i+3]=v.w;
    s  += v.x + v.y + v.z + v.w;
    sq += v.x*v.x + v.y*v.y + v.z*v.z + v.w*v.w;
  }
  s  += __shfl_xor(s, 1);  s  += __shfl_xor(s, 2);
  sq += __shfl_xor(sq, 1); sq += __shfl_xor(sq, 2);
  {
    const float mean = s * 0.0078125f;
    const float var  = sq * 0.0078125f - mean*mean;
    const float rs   = rsqrtf(var + 1e-6f);
#pragma unroll
    for (int i = 0; i < 8; ++i) {
      u16x4 o;
#pragma unroll
      for (int j2 = 0; j2 < 4; ++j2) {
        int c = qtr*32 + 4*i + j2;
        o[j2] = f2bf((xr[4*i+j2]-mean)*rs*n1s[c] + n1b[c]);
      }
      *reinterpret_cast<u16x4*>(&ldsA[t*140 + qtr*32 + 4*i]) = o;
    }
  }
  if (tid < 64) {
    int twd = tid >> 4, twh = (tid >> 2) & 3, tww = tid & 3;
    int rd = (bd == 7)  ? (twd < 2 ? 1 : 2) : 0;
    int rh = (bh == 15) ? (twh < 2 ? 1 : 2) : 0;
    int rw = (bwi == 15)? (tww < 2 ? 1 : 2) : 0;
    rid_s[tid] = rd*9 + rh*3 + rw;
  }
  __syncthreads();   // B0

  unsigned short* qldsH  = &ldsB[w*6912];
  unsigned short* kldsH  = qldsH + 2304;
  unsigned short* vTldsH = qldsH + 4608;
  unsigned short* pldsH  = qldsH;          // overlays q+k

  // ---- phase 1: QKV (transposed).  wave w computes head w's Q,K (as [tok][dim]) and V^T ----
  {
    bf16x8 Bx[4][4];
#pragma unroll
    for (int nt = 0; nt < 4; ++nt)
#pragma unroll
      for (int kp = 0; kp < 4; ++kp)
        Bx[nt][kp] = frag_ld(ldsA, 140, nt, kp, lane);

#pragma unroll
    for (int part = 0; part < 3; ++part) {     // 0=Q,1=K,2=V
#pragma unroll
      for (int mi = 0; mi < 2; ++mi) {
        const int mt = part*8 + 2*w + mi;
        bf16x8 A[4];
#pragma unroll
        for (int kp = 0; kp < 4; ++kp) A[kp] = afrag_ld(wqkv, mt, 4, kp, lane);
#pragma unroll
        for (int nt = 0; nt < 4; ++nt) {
          f32x4 acc = {0.f,0.f,0.f,0.f};
#pragma unroll
          for (int kp = 0; kp < 4; ++kp) acc = MFMA16(A[kp], Bx[nt][kp], acc);
          if (part == 0) {
#pragma unroll
            for (int r2 = 0; r2 < 4; ++r2)
              qldsH[(16*nt + l15)*36 + mi*16 + 4*g + r2] = f2bf(acc[r2]*0.17677669529663687f);
          } else if (part == 1) {
#pragma unroll
            for (int r2 = 0; r2 < 4; ++r2)
              kldsH[(16*nt + l15)*36 + mi*16 + 4*g + r2] = f2bf(acc[r2]);
          } else {
#pragma unroll
            for (int r2 = 0; r2 < 4; ++r2)
              vTldsH[(mi*16 + 4*g + r2)*72 + 16*nt + l15] = f2bf(acc[r2]);
          }
        }
      }
    }
  }
  __syncthreads();   // B1 (also: last reads of xn in arena A)

  // ---- phase 2: attention, wave = head ----
  {
    // S^T[key][q] = K @ Q^T
    bf16x8 Ak[4], Bq[4];
#pragma unroll
    for (int mt = 0; mt < 4; ++mt) Ak[mt] = frag_ld(kldsH, 36, mt, 0, lane);
#pragma unroll
    for (int nt = 0; nt < 4; ++nt) Bq[nt] = frag_ld(qldsH, 36, nt, 0, lane);
    f32x4 sacc[4][4];
#pragma unroll
    for (int mt = 0; mt < 4; ++mt)
#pragma unroll
      for (int nt = 0; nt < 4; ++nt) {
        f32x4 z = {0.f,0.f,0.f,0.f};
        sacc[mt][nt] = MFMA16(Ak[mt], Bq[nt], z);
      }
    // + relative-position bias + shifted-window mask
    int ridq[4];
#pragma unroll
    for (int nt = 0; nt < 4; ++nt) ridq[nt] = rid_s[16*nt + l15];
#pragma unroll
    for (int mt = 0; mt < 4; ++mt) {
#pragma unroll
      for (int r2 = 0; r2 < 4; ++r2) {
        const int key = 16*mt + 4*g + r2;
        const int ridk = rid_s[key];
#pragma unroll
        for (int nt = 0; nt < 4; ++nt) {
          const int q = 16*nt + l15;
          float add = biasT[(w*64 + key)*64 + q];
          if (ridk != ridq[nt]) add -= 100.f;
          sacc[mt][nt][r2] += add;
        }
      }
    }
    // softmax over keys (in-lane 16 + shfl_xor 16/32), write P to p_lds[q][key]
#pragma unroll
    for (int nt = 0; nt < 4; ++nt) {
      float mx = -1e30f;
#pragma unroll
      for (int mt = 0; mt < 4; ++mt)
#pragma unroll
        for (int r2 = 0; r2 < 4; ++r2) mx = fmaxf(mx, sacc[mt][nt][r2]);
      mx = fmaxf(mx, __shfl_xor(mx, 16));
      mx = fmaxf(mx, __shfl_xor(mx, 32));
      float sum = 0.f;
#pragma unroll
      for (int mt = 0; mt < 4; ++mt)
#pragma unroll
        for (int r2 = 0; r2 < 4; ++r2) {
          float p = __expf(sacc[mt][nt][r2] - mx);
          sacc[mt][nt][r2] = p; sum += p;
        }
      sum += __shfl_xor(sum, 16);
      sum += __shfl_xor(sum, 32);
      const float inv = 1.f / sum;
#pragma unroll
      for (int mt = 0; mt < 4; ++mt)
#pragma unroll
        for (int r2 = 0; r2 < 4; ++r2)
          pldsH[(16*nt + l15)*72 + 16*mt + 4*g + r2] = f2bf(sacc[mt][nt][r2]*inv);
    }
    // O^T = V^T @ P^T  -> arena A as o[tok][ch] (head's 32 columns)
    bf16x8 Av[2][2];
#pragma unroll
    for (int mt2 = 0; mt2 < 2; ++mt2)
#pragma unroll
      for (int kp = 0; kp < 2; ++kp) Av[mt2][kp] = frag_ld(vTldsH, 72, mt2, kp, lane);
#pragma unroll
    for (int nt = 0; nt < 4; ++nt) {
      bf16x8 Bp[2];
#pragma unroll
      for (int kp = 0; kp < 2; ++kp) Bp[kp] = frag_ld(pldsH, 72, nt, kp, lane);
#pragma unroll
      for (int mt2 = 0; mt2 < 2; ++mt2) {
        f32x4 acc = {0.f,0.f,0.f,0.f};
        acc = MFMA16(Av[mt2][0], Bp[0], acc);
        acc = MFMA16(Av[mt2][1], Bp[1], acc);
#pragma unroll
        for (int r2 = 0; r2 < 4; ++r2)
          ldsA[(16*nt + l15)*140 + w*32 + mt2*16 + 4*g + r2] = f2bf(acc[r2]);
      }
    }
  }
  __syncthreads();   // B2

  // ---- phase 3: proj (transposed) ----
  {
    bf16x8 Bo[4][4];
#pragma unroll
    for (int nt = 0; nt < 4; ++nt)
#pragma unroll
      for (int kp = 0; kp < 4; ++kp)
        Bo[nt][kp] = frag_ld(ldsA, 140, nt, kp, lane);
    f32x4 pacc[2][4];
#pragma unroll
    for (int mi = 0; mi < 2; ++mi) {
      const int mt = 2*w + mi;
      bf16x8 A[4];
#pragma unroll
      for (int kp = 0; kp < 4; ++kp) A[kp] = afrag_ld(wproj, mt, 4, kp, lane);
#pragma unroll
      for (int nt = 0; nt < 4; ++nt) {
        f32x4 acc = {0.f,0.f,0.f,0.f};
#pragma unroll
        for (int kp = 0; kp < 4; ++kp) acc = MFMA16(A[kp], Bo[nt][kp], acc);
        pacc[mi][nt] = acc;
      }
    }
#pragma unroll
    for (int mi = 0; mi < 2; ++mi)
#pragma unroll
      for (int r2 = 0; r2 < 4; ++r2) {
        const float pb = projb[16*(2*w+mi) + 4*g + r2];
#pragma unroll
        for (int nt = 0; nt < 4; ++nt) pacc[mi][nt][r2] += pb;
      }
    __syncthreads();   // B3: all reads of o done before staging overwrite
#pragma unroll
    for (int mi = 0; mi < 2; ++mi)
#pragma unroll
      for (int nt = 0; nt < 4; ++nt)
#pragma unroll
        for (int r2 = 0; r2 < 4; ++r2)
          ldsA[(16*nt + l15)*140 + 16*(2*w+mi) + 4*g + r2] = f2bf(pacc[mi][nt][r2]);
  }
  __syncthreads();   // B4

  // ---- phase 4: residual + LN2 (per token), write xn2 bf16 to arena A ----
  {
    float s2 = 0.f, sq2 = 0.f;
#pragma unroll
    for (int i = 0; i < 8; ++i) {
      u16x4 av = *reinterpret_cast<const u16x4*>(&ldsA[t*140 + qtr*32 + 4*i]);
#pragma unroll
      for (int j2 = 0; j2 < 4; ++j2) {
        float v2 = xr[4*i+j2] + bf2f(av[j2]);
        xr[4*i+j2] = v2;
        s2 += v2; sq2 += v2*v2;
      }
    }
    s2  += __shfl_xor(s2, 1);  s2  += __shfl_xor(s2, 2);
    sq2 += __shfl_xor(sq2, 1); sq2 += __shfl_xor(sq2, 2);
    const float mean2 = s2*0.0078125f;
    const float rs2 = rsqrtf(sq2*0.0078125f - mean2*mean2 + 1e-6f);
#pragma unroll
    for (int i = 0; i < 8; ++i) {
      u16x4 o;
#pragma unroll
      for (int j2 = 0; j2 < 4; ++j2) {
        int c = qtr*32 + 4*i + j2;
        o[j2] = f2bf((xr[4*i+j2]-mean2)*rs2*n2s[c] + n2b[c]);
      }
      *reinterpret_cast<u16x4*>(&ldsA[t*140 + qtr*32 + 4*i]) = o;
    }
  }
  __syncthreads();   // B5

  // ---- phase 5: MLP (transposed), hidden in 2 chunks of 256 through ldsB ----
  {
    unsigned short* hid = ldsB;   // [64][268]
    bf16x8 Bn[4][4];
#pragma unroll
    for (int nt = 0; nt < 4; ++nt)
#pragma unroll
      for (int kp = 0; kp < 4; ++kp)
        Bn[nt][kp] = frag_ld(ldsA, 140, nt, kp, lane);

    f32x4 macc[2][4];
#pragma unroll
    for (int mi = 0; mi < 2; ++mi)
#pragma unroll
      for (int nt = 0; nt < 4; ++nt) { f32x4 z = {0.f,0.f,0.f,0.f}; macc[mi][nt] = z; }

#pragma unroll
    for (int cc = 0; cc < 2; ++cc) {
      // MLP1: this wave's 4 hidden m-tiles of this chunk, gelu, -> hid
#pragma unroll
      for (int mi = 0; mi < 4; ++mi) {
        const int mtl = 4*w + mi;           // local hid tile (0..15)
        const int mtg = cc*16 + mtl;        // global w1 tile (0..31)
        bf16x8 A[4];
#pragma unroll
        for (int kp = 0; kp < 4; ++kp) A[kp] = afrag_ld(w1f, mtg, 4, kp, lane);
#pragma unroll
        for (int nt = 0; nt < 4; ++nt) {
          f32x4 acc = {0.f,0.f,0.f,0.f};
#pragma unroll
          for (int kp = 0; kp < 4; ++kp) acc = MFMA16(A[kp], Bn[nt][kp], acc);
#pragma unroll
          for (int r2 = 0; r2 < 4; ++r2) {
            const int hch = 16*mtg + 4*g + r2;
            float v2 = acc[r2] + b1[hch];
            float gg = 0.7978845608028654f*(v2 + 0.044715f*v2*v2*v2);
            float ge = v2 / (1.f + __expf(-2.f*gg));   // 0.5x(1+tanh(gg))
            hid[(16*nt + l15)*268 + 16*mtl + 4*g + r2] = f2bf(ge);
          }
        }
      }
      __syncthreads();
      // MLP2 partial over this chunk's 256 hidden channels
#pragma unroll
      for (int mi = 0; mi < 2; ++mi) {
        const int mt = 2*w + mi;
        bf16x8 A2[8];
#pragma unroll
        for (int kp = 0; kp < 8; ++kp) A2[kp] = afrag_ld(w2f, mt, 16, cc*8 + kp, lane);
#pragma unroll
        for (int nt = 0; nt < 4; ++nt) {
          f32x4 acc = macc[mi][nt];
#pragma unroll
          for (int kp = 0; kp < 8; ++kp) {
            bf16x8 Bh = frag_ld(hid, 268, nt, kp, lane);
            acc = MFMA16(A2[kp], Bh, acc);
          }
          macc[mi][nt] = acc;
        }
      }
      __syncthreads();
    }
    // mlp output (+b2) -> arena A staging
#pragma unroll
    for (int mi = 0; mi < 2; ++mi)
#pragma unroll
      for (int r2 = 0; r2 < 4; ++r2) {
        const float bb = b2[16*(2*w+mi) + 4*g + r2];
#pragma unroll
        for (int nt = 0; nt < 4; ++nt)
          ldsA[(16*nt + l15)*140 + 16*(2*w+mi) + 4*g + r2] = f2bf(macc[mi][nt][r2] + bb);
      }
  }
  __syncthreads();

  // ---- phase 6: out = x_res + mlp (per token, coalesced f32 stores) ----
  {
    float* orow = out + tokl*128 + qtr*32;
#pragma unroll
    for (int i = 0; i < 8; ++i) {
      u16x4 mv = *reinterpret_cast<const u16x4*>(&ldsA[t*140 + qtr*32 + 4*i]);
      float4 v;
      v.x = xr[4*i+0] + bf2f(mv[0]);
      v.y = xr[4*i+1] + bf2f(mv[1]);
      v.z = xr[4*i+2] + bf2f(mv[2]);
      v.w = xr[4*i+3] + bf2f(mv[3]);
      reinterpret_cast<float4*>(orow)[i] = v;
    }
  }
}

extern "C" void kernel_launch(void* const* d_in, const int* in_sizes, int n_in,
                              void* d_out, int out_size, void* d_ws, size_t ws_size,
                              hipStream_t stream) {
  (void)in_sizes; (void)n_in; (void)out_size; (void)ws_size;
  const float* x    = (const float*)d_in[0];
  // d_in[1] (mask) is recomputed analytically in-kernel
  const float* n1s  = (const float*)d_in[2];
  const float* n1b  = (const float*)d_in[3];
  const float* qkvw = (const float*)d_in[4];
  const float* tbl  = (const float*)d_in[5];
  const float* pw   = (const float*)d_in[6];
  const float* pb   = (const float*)d_in[7];
  const float* n2s  = (const float*)d_in[8];
  const float* n2b  = (const float*)d_in[9];
  const float* w1   = (const float*)d_in[10];
  const float* b1   = (const float*)d_in[11];
  const float* w2   = (const float*)d_in[12];
  const float* b2   = (const float*)d_in[13];
  float* out = (float*)d_out;

  // ws layout (u16 units): wqkv 24*4*64*8 | wproj 8*4*64*8 | w1 32*4*64*8 | w2 8*16*64*8 | biasT f32 16384
  unsigned short* wqkv_f  = (unsigned short*)d_ws;
  unsigned short* wproj_f = wqkv_f  + 24*4*64*8;
  unsigned short* w1_f    = wproj_f + 8*4*64*8;
  unsigned short* w2_f    = w1_f    + 32*4*64*8;
  float*          biasT   = (float*)(w2_f + 8*16*64*8);

  pack_w_kernel<<<(24*4*64 + 255)/256, 256, 0, stream>>>(qkvw, wqkv_f, 24, 4, 384);
  pack_w_kernel<<<(8*4*64  + 255)/256, 256, 0, stream>>>(pw,   wproj_f, 8, 4, 128);
  pack_w_kernel<<<(32*4*64 + 255)/256, 256, 0, stream>>>(w1,   w1_f,   32, 4, 512);
  pack_w_kernel<<<(8*16*64 + 255)/256, 256, 0, stream>>>(w2,   w2_f,    8,16, 128);
  prep_bias_kernel<<<(4*64*64 + 255)/256, 256, 0, stream>>>(tbl, biasT);

  swin_block_kernel<<<4096, 256, 0, stream>>>(x, n1s, n1b, wqkv_f, biasT, wproj_f, pb,
                                              n2s, n2b, w1_f, b1, w2_f, b2, out);
}